// Round 2
// baseline (650.192 us; speedup 1.0000x reference)
//
#include <hip/hip_runtime.h>

#define N_NODES 50000
#define W_IN    256
#define W_OUT   256
#define HEADS   8
#define NUM_T   3
#define N_EDGES 800000
#define NEG_SLOPE 0.2f

#define NB      128           // coarse buckets (98 used)
#define BSH     9             // bucket = dst >> 9  (512 nodes/bucket)
#define BNODES  512
#define P1_EPT  16            // edges per thread in partition kernels
#define P1_CHUNK (256 * P1_EPT)   // 4096 edges per block
#define P1_BLOCKS ((N_EDGES + P1_CHUNK - 1) / P1_CHUNK)  // 196
#define NB_USED ((N_NODES + BNODES - 1) / BNODES)        // 98

#define GEMM_BLOCKS ((N_NODES + 63) / 64)       // 782
#define GATHER_BLOCKS ((N_NODES + 3) / 4)       // 12500
#define FUSE_STRIDE 17                           // 1 gemm block per 16 gather blocks
#define FUSED_BLOCKS (GEMM_BLOCKS + GATHER_BLOCKS)  // 13282
#define GEMM_SMEM 29696                          // As 5120 + Bs 20480 + els 2048 + ers 2048

typedef __attribute__((ext_vector_type(8))) short bf16x8;
typedef __attribute__((ext_vector_type(4))) float f32x4;

__device__ __forceinline__ unsigned short f2b(float f) {
    unsigned u = __float_as_uint(f);
    u = (u + 0x7fffu + ((u >> 16) & 1u)) >> 16;
    return (unsigned short)u;
}
__device__ __forceinline__ float blo(unsigned u) { return __uint_as_float(u << 16); }
__device__ __forceinline__ float bhi(unsigned u) { return __uint_as_float(u & 0xffff0000u); }

// ---------------------------------------------------------------------------
// x fp32 -> bf16 (RNE). 12500 blocks * 256 threads * 4 elems = 12.8M exact.
// ---------------------------------------------------------------------------
__global__ __launch_bounds__(256) void convert_x(const float* __restrict__ x,
                                                 unsigned short* __restrict__ xb) {
    const size_t i = ((size_t)blockIdx.x * 256 + threadIdx.x) * 4;
    const float4 v = *(const float4*)(x + i);
    ushort4 o;
    o.x = f2b(v.x); o.y = f2b(v.y); o.z = f2b(v.z); o.w = f2b(v.w);
    *(ushort4*)(xb + i) = o;
}

// ---------------------------------------------------------------------------
// W fp32 [t][k][n] -> bf16 transposed [t][n][k].
// ---------------------------------------------------------------------------
__global__ __launch_bounds__(256) void convert_W(const float* __restrict__ Wsrc,
                                                 unsigned short* __restrict__ Wt) {
    const int t = blockIdx.y;
    const int gid = blockIdx.x * 256 + threadIdx.x;  // 0..65535
    const int k = gid >> 8, n = gid & 255;
    Wt[(size_t)t * 65536 + (size_t)n * 256 + k] = f2b(Wsrc[(size_t)t * 65536 + gid]);
}

// ---------------------------------------------------------------------------
// Partition level 1a: coarse histogram (LDS-aggregated).
// ---------------------------------------------------------------------------
__global__ __launch_bounds__(256) void p1_hist(const int* __restrict__ adj,
                                               int* __restrict__ bucket_cnt) {
    __shared__ int lh[NB];
    const int t = blockIdx.y;
    const int tid = threadIdx.x;
    if (tid < NB) lh[tid] = 0;
    __syncthreads();

    const int* dstp = adj + (size_t)t * 2 * N_EDGES + N_EDGES;
    const int e0 = blockIdx.x * P1_CHUNK + tid * P1_EPT;
#pragma unroll
    for (int i = 0; i < P1_EPT; ++i) {
        const int e = e0 + i;
        if (e < N_EDGES) atomicAdd(&lh[dstp[e] >> BSH], 1);
    }
    __syncthreads();
    if (tid < NB && lh[tid] > 0) atomicAdd(&bucket_cnt[t * NB + tid], lh[tid]);
}

// ---------------------------------------------------------------------------
// Partition level 1b: scan 128 bucket counts per type. One block, 128 thr.
// ---------------------------------------------------------------------------
__global__ __launch_bounds__(128) void p1_scan(const int* __restrict__ bucket_cnt,
                                               int* __restrict__ bucket_ptr,
                                               int* __restrict__ bucket_cur) {
    __shared__ int s[NB];
    const int tid = threadIdx.x;
    for (int t = 0; t < NUM_T; ++t) {
        const int v = bucket_cnt[t * NB + tid];
        s[tid] = v;
        __syncthreads();
        for (int off = 1; off < NB; off <<= 1) {
            int o = (tid >= off) ? s[tid - off] : 0;
            __syncthreads();
            s[tid] += o;
            __syncthreads();
        }
        const int incl = s[tid];
        const int excl = incl - v;
        bucket_ptr[t * (NB + 1) + tid] = excl;
        bucket_cur[t * NB + tid] = excl;
        if (tid == NB - 1) bucket_ptr[t * (NB + 1) + NB] = incl;
        __syncthreads();
    }
}

// ---------------------------------------------------------------------------
// Partition level 1c v2: LDS counting-sort, then contiguous flush.
// ---------------------------------------------------------------------------
__global__ __launch_bounds__(256) void p1_scatter(const int* __restrict__ adj,
                                                  int* __restrict__ bucket_cur,
                                                  uint2* __restrict__ part) {
    __shared__ int lh[NB];
    __shared__ int loff[NB];
    __shared__ int lbase[NB];
    __shared__ uint2 buf[P1_CHUNK];   // 32 KB
    const int t = blockIdx.y;
    const int tid = threadIdx.x;
    const int lane = tid & 63;
    const int wave = tid >> 6;
    if (tid < NB) lh[tid] = 0;
    __syncthreads();

    const int* srcp = adj + (size_t)t * 2 * N_EDGES;
    const int* dstp = srcp + N_EDGES;
    const int e0 = blockIdx.x * P1_CHUNK + tid * P1_EPT;

    int es[P1_EPT], ed[P1_EPT], rk[P1_EPT];
#pragma unroll
    for (int i = 0; i < P1_EPT; ++i) {
        const int e = e0 + i;
        if (e < N_EDGES) {
            es[i] = srcp[e];
            ed[i] = dstp[e];
            rk[i] = atomicAdd(&lh[ed[i] >> BSH], 1);
        } else {
            ed[i] = -1;
        }
    }
    __syncthreads();

    // global window reserve (one atomic per non-empty bucket)
    if (tid < NB && lh[tid] > 0)
        lbase[tid] = atomicAdd(&bucket_cur[t * NB + tid], lh[tid]);
    // local exclusive scan of lh -> loff (wave 0, 2 buckets/lane)
    if (wave == 0) {
        const int c0 = lh[lane * 2], c1 = lh[lane * 2 + 1];
        const int s = c0 + c1;
        int run = s;
        for (int off = 1; off < 64; off <<= 1) {
            const int o = __shfl_up(run, off);
            if (lane >= off) run += o;
        }
        const int base = run - s;
        loff[lane * 2] = base;
        loff[lane * 2 + 1] = base + c0;
    }
    __syncthreads();

#pragma unroll
    for (int i = 0; i < P1_EPT; ++i)
        if (ed[i] >= 0)
            buf[loff[ed[i] >> BSH] + rk[i]] =
                make_uint2((unsigned)es[i], (unsigned)ed[i]);
    __syncthreads();

    uint2* pt = part + (size_t)t * N_EDGES;
    int nvalid = N_EDGES - blockIdx.x * P1_CHUNK;
    if (nvalid > P1_CHUNK) nvalid = P1_CHUNK;
    for (int idx = tid; idx < nvalid; idx += 256) {
        const uint2 e = buf[idx];
        const int b = (int)(e.y >> BSH);
        pt[lbase[b] + (idx - loff[b])] = e;
    }
}

// ---------------------------------------------------------------------------
// Partition level 2: per-bucket local CSR. One block per (bucket, type).
// ---------------------------------------------------------------------------
__global__ __launch_bounds__(256) void p2_csr(const uint2* __restrict__ part,
                                              const int* __restrict__ bucket_ptr,
                                              int* __restrict__ row_ptr_all,
                                              int* __restrict__ csr_all) {
    __shared__ int sc[BNODES];
    const int b = blockIdx.x;
    const int t = blockIdx.y;
    const int tid = threadIdx.x;
    const int lane = tid & 63;
    const int wave = tid >> 6;

    const uint2* pt = part + (size_t)t * N_EDGES;
    int* row_ptr = row_ptr_all + (size_t)t * (N_NODES + 1);
    int* csr = csr_all + (size_t)t * N_EDGES;

    const int bp0 = bucket_ptr[t * (NB + 1) + b];
    const int bp1 = bucket_ptr[t * (NB + 1) + b + 1];
    const int node0 = b * BNODES;
    int nn = N_NODES - node0; if (nn > BNODES) nn = BNODES;

    sc[tid] = 0; sc[tid + 256] = 0;
    __syncthreads();

    for (int idx = bp0 + tid; idx < bp1; idx += 256)
        atomicAdd(&sc[pt[idx].y - node0], 1);
    __syncthreads();

    if (wave == 0) {
        int v[8], ex[8];
        int s = 0;
#pragma unroll
        for (int i = 0; i < 8; ++i) { v[i] = sc[lane * 8 + i]; ex[i] = s; s += v[i]; }
        int run = s;
        for (int off = 1; off < 64; off <<= 1) {
            int o = __shfl_up(run, off);
            if (lane >= off) run += o;
        }
        const int base = run - s;
#pragma unroll
        for (int i = 0; i < 8; ++i) sc[lane * 8 + i] = base + ex[i];
    }
    __syncthreads();

    for (int i = tid; i < nn; i += 256) row_ptr[node0 + i] = bp0 + sc[i];
    if (b == NB_USED - 1 && tid == 0) row_ptr[N_NODES] = N_EDGES;
    __syncthreads();

    for (int idx = bp0 + tid; idx < bp1; idx += 256) {
        const uint2 e = pt[idx];
        const int pos = bp0 + atomicAdd(&sc[e.y - node0], 1);
        csr[pos] = (int)e.x;
    }
}

// ---------------------------------------------------------------------------
// GEMM + fused attention-score body (shared by standalone + fused kernels).
// smem carve: As[64*40] @0 (5120 B), Bs[256*40] @5120 (20480 B),
//             els[512] @25600 (2048 B), ers[512] @27648 (2048 B).
// ---------------------------------------------------------------------------
__device__ __forceinline__ void gemm_body(const int bm, const int tid,
                                          unsigned char* smem,
                                          const unsigned short* __restrict__ xb,
                                          const unsigned short* __restrict__ Wt,
                                          const float* __restrict__ al,
                                          const float* __restrict__ ar,
                                          unsigned short* __restrict__ H,
                                          float* __restrict__ el,
                                          float* __restrict__ er) {
    unsigned short* As = (unsigned short*)smem;
    unsigned short* Bs = (unsigned short*)(smem + 5120);
    float* els = (float*)(smem + 25600);
    float* ers = (float*)(smem + 27648);

    const int wave = tid >> 6;
    const int lane = tid & 63;
    const int quad = lane >> 4;
    const int l16 = lane & 15;
    const int m0 = bm * 64;

    f32x4 acc[4][4] = {};

    const int arow = tid >> 2;
    const int achunk = (tid & 3) * 8;
    int gm = m0 + arow;
    if (gm > N_NODES - 1) gm = N_NODES - 1;
    const unsigned short* aptr = xb + (size_t)gm * W_IN + achunk;

    for (int k0 = 0; k0 < W_IN; k0 += 32) {
        const uint4 av = *(const uint4*)(aptr + k0);
        *(uint4*)&As[arow * 40 + achunk] = av;
#pragma unroll
        for (int i = 0; i < 4; ++i) {
            const int idx = i * 256 + tid;
            const int brow = idx >> 2;
            const int bch = (idx & 3) * 8;
            const uint4 bv = *(const uint4*)(Wt + (size_t)brow * W_IN + k0 + bch);
            *(uint4*)&Bs[brow * 40 + bch] = bv;
        }
        __syncthreads();

        bf16x8 af[4], bfr[4];
#pragma unroll
        for (int mi = 0; mi < 4; ++mi)
            af[mi] = *(const bf16x8*)&As[(mi * 16 + l16) * 40 + quad * 8];
#pragma unroll
        for (int ni = 0; ni < 4; ++ni)
            bfr[ni] = *(const bf16x8*)&Bs[(wave * 64 + ni * 16 + l16) * 40 + quad * 8];
#pragma unroll
        for (int mi = 0; mi < 4; ++mi)
#pragma unroll
            for (int ni = 0; ni < 4; ++ni)
                acc[mi][ni] = __builtin_amdgcn_mfma_f32_16x16x32_bf16(
                    af[mi], bfr[ni], acc[mi][ni], 0, 0, 0);
        __syncthreads();
    }

#pragma unroll
    for (int mi = 0; mi < 4; ++mi)
#pragma unroll
        for (int reg = 0; reg < 4; ++reg) {
            const int gr = m0 + mi * 16 + quad * 4 + reg;
            if (gr < N_NODES)
#pragma unroll
                for (int ni = 0; ni < 4; ++ni)
                    H[(size_t)gr * W_OUT + wave * 64 + ni * 16 + l16] =
                        f2b(acc[mi][ni][reg]);
        }

    float al4[4], ar4[4];
#pragma unroll
    for (int ni = 0; ni < 4; ++ni) {
        const int c = wave * 64 + ni * 16 + l16;
        al4[ni] = al[c];
        ar4[ni] = ar[c];
    }
#pragma unroll
    for (int mi = 0; mi < 4; ++mi) {
        float pl[4][2] = {}, pr[4][2] = {};
#pragma unroll
        for (int ni = 0; ni < 4; ++ni) {
            const int hl = ni >> 1;
#pragma unroll
            for (int reg = 0; reg < 4; ++reg) {
                pl[reg][hl] += acc[mi][ni][reg] * al4[ni];
                pr[reg][hl] += acc[mi][ni][reg] * ar4[ni];
            }
        }
#pragma unroll
        for (int off = 1; off < 16; off <<= 1)
#pragma unroll
            for (int reg = 0; reg < 4; ++reg)
#pragma unroll
                for (int hl = 0; hl < 2; ++hl) {
                    pl[reg][hl] += __shfl_xor(pl[reg][hl], off);
                    pr[reg][hl] += __shfl_xor(pr[reg][hl], off);
                }
        if (l16 == 0)
#pragma unroll
            for (int reg = 0; reg < 4; ++reg)
#pragma unroll
                for (int hl = 0; hl < 2; ++hl) {
                    const int row = mi * 16 + quad * 4 + reg;
                    els[row * 8 + wave * 2 + hl] = pl[reg][hl];
                    ers[row * 8 + wave * 2 + hl] = pr[reg][hl];
                }
    }
    __syncthreads();

    int nn = N_NODES - m0; if (nn > 64) nn = 64;
    const int nn8 = nn * 8;
    const int i = tid * 4;
    if (i < nn8) {
        *(float4*)(el + (size_t)m0 * 8 + i) = *(float4*)&els[i];
        *(float4*)(er + (size_t)m0 * 8 + i) = *(float4*)&ers[i];
    }
}

// ---------------------------------------------------------------------------
// Gather v3 body (round-0 structure, 24 VGPR, known 65.4 us/dispatch):
// 2 edges per wave-instruction + 1-deep software pipeline.
// ---------------------------------------------------------------------------
__device__ __forceinline__ void gather_body(const int node, const int lane,
                                            const int* __restrict__ csr_src,
                                            const int* __restrict__ row_ptr,
                                            const float* __restrict__ el,
                                            const float* __restrict__ er,
                                            const unsigned short* __restrict__ H,
                                            unsigned short* __restrict__ ot) {
    const int half = lane >> 5;
    const int d8 = lane & 31;
    const int hh = d8 >> 2;

    const int beg = row_ptr[node];
    const int deg = row_ptr[node + 1] - beg;
    const float erv = er[(size_t)node * HEADS + hh];

    float2 acc[4] = {};
    float ssum = 0.f;

    if (deg > 0) {
        int mysrc = (lane < deg) ? csr_src[beg + lane] : 0;
        const int npairs = (deg + 1) >> 1;

        // prologue: load pair 0 (edge ei = half)
        int src0 = __shfl(mysrc, half);
        uint4 u0 = *(const uint4*)(H + (size_t)src0 * W_OUT + d8 * 8);
        float elv0 = el[(size_t)src0 * HEADS + hh];

        for (int q = 0; q < npairs; ++q) {
            int src1 = 0; uint4 u1 = u0; float elv1 = 0.f;
            const int q1 = q + 1;
            if (q1 < npairs) {
                if ((q1 & 31) == 0) {
                    const int cb = beg + (q1 >> 5) * 64;
                    mysrc = (cb + lane < beg + deg) ? csr_src[cb + lane] : 0;
                }
                src1 = __shfl(mysrc, (2 * q1 + half) & 63);
                u1 = *(const uint4*)(H + (size_t)src1 * W_OUT + d8 * 8);
                elv1 = el[(size_t)src1 * HEADS + hh];
            }
            float v = elv0 + erv;
            v = (v > 0.f) ? v : NEG_SLOPE * v;
            const float w = (2 * q + half < deg) ? __expf(v) : 0.f;
            acc[0].x += w * blo(u0.x); acc[0].y += w * bhi(u0.x);
            acc[1].x += w * blo(u0.y); acc[1].y += w * bhi(u0.y);
            acc[2].x += w * blo(u0.z); acc[2].y += w * bhi(u0.z);
            acc[3].x += w * blo(u0.w); acc[3].y += w * bhi(u0.w);
            ssum += w;
            src0 = src1; u0 = u1; elv0 = elv1;
        }
    }

#pragma unroll
    for (int i = 0; i < 4; ++i) {
        acc[i].x += __shfl_xor(acc[i].x, 32);
        acc[i].y += __shfl_xor(acc[i].y, 32);
    }
    ssum += __shfl_xor(ssum, 32);

    if (half == 0) {
        const float inv = 1.f / (ssum + 1e-9f);
        unsigned short o8[8];
#pragma unroll
        for (int i = 0; i < 4; ++i) {
            o8[2 * i]     = f2b(acc[i].x * inv);
            o8[2 * i + 1] = f2b(acc[i].y * inv);
        }
        *(uint4*)(ot + (size_t)node * W_OUT + d8 * 8) = *(const uint4*)o8;
    }
}

// ---------------------------------------------------------------------------
// Standalone wrappers.
// ---------------------------------------------------------------------------
__global__ __launch_bounds__(256) void gemm_fused(const unsigned short* __restrict__ xb,
                                                  const unsigned short* __restrict__ Wt,
                                                  const float* __restrict__ al,
                                                  const float* __restrict__ ar,
                                                  unsigned short* __restrict__ H,
                                                  float* __restrict__ el,
                                                  float* __restrict__ er) {
    __shared__ __attribute__((aligned(16))) unsigned char smem[GEMM_SMEM];
    gemm_body(blockIdx.x, threadIdx.x, smem, xb, Wt, al, ar, H, el, er);
}

__global__ __launch_bounds__(256) void gat_gather(const int* __restrict__ csr_src,
                                                  const int* __restrict__ row_ptr,
                                                  const float* __restrict__ el,
                                                  const float* __restrict__ er,
                                                  const unsigned short* __restrict__ H,
                                                  unsigned short* __restrict__ ot) {
    const int node = (blockIdx.x * blockDim.x + threadIdx.x) >> 6;
    if (node >= N_NODES) return;
    gather_body(node, threadIdx.x & 63, csr_src, row_ptr, el, er, H, ot);
}

// ---------------------------------------------------------------------------
// Block-specialized fusion: blocks with (blockIdx.x % 17 == 0) run the gemm
// for type t+1 (782 blocks); the rest (12500) run the v3 gather for type t.
// No intra-kernel data dependency: gather reads the H/el/er produced by the
// PREVIOUS dispatch; gemm writes the other buffer of the double-buffer pair.
// MFMA pipe (gemm waves) and VMEM path (gather waves) co-schedule per CU.
// ---------------------------------------------------------------------------
__global__ __launch_bounds__(256) void fused_gg(
    const unsigned short* __restrict__ xb, const unsigned short* __restrict__ Wt,
    const float* __restrict__ al, const float* __restrict__ ar,
    unsigned short* __restrict__ Hout, float* __restrict__ el_out,
    float* __restrict__ er_out,
    const int* __restrict__ csr_src, const int* __restrict__ row_ptr,
    const float* __restrict__ el_in, const float* __restrict__ er_in,
    const unsigned short* __restrict__ Hin, unsigned short* __restrict__ ot) {
    __shared__ __attribute__((aligned(16))) unsigned char smem[GEMM_SMEM];
    const int p = blockIdx.x;
    const int q = p / FUSE_STRIDE;
    if (p % FUSE_STRIDE == 0) {
        // q in 0..781 (17*781 = 13277 <= 13281)
        gemm_body(q, threadIdx.x, smem, xb, Wt, al, ar, Hout, el_out, er_out);
    } else {
        const int gb = p - q - 1;          // 0..12499, monotone
        const int node = gb * 4 + (threadIdx.x >> 6);
        if (node < N_NODES)
            gather_body(node, threadIdx.x & 63, csr_src, row_ptr, el_in, er_in,
                        Hin, ot);
    }
}

// ---------------------------------------------------------------------------
// Semantic attention combine: bf16 ot inputs, fp32 out.
// ---------------------------------------------------------------------------
__global__ __launch_bounds__(256) void combine(const unsigned short* __restrict__ ot0,
                                               const unsigned short* __restrict__ ot1,
                                               const unsigned short* __restrict__ ot2,
                                               const float* __restrict__ bias,
                                               const float* __restrict__ att_w,
                                               const float* __restrict__ att_b,
                                               float* __restrict__ out) {
    const int gw = (blockIdx.x * blockDim.x + threadIdx.x) >> 6;
    const int lane = threadIdx.x & 63;
    if (gw >= N_NODES) return;

    const float4 aw = *(const float4*)(att_w + lane * 4);
    const size_t base = (size_t)gw * W_OUT + lane * 4;

    float4 v[NUM_T];
    float p[NUM_T];
    const unsigned short* ots[NUM_T] = {ot0, ot1, ot2};
#pragma unroll
    for (int t = 0; t < NUM_T; ++t) {
        const uint2 u = *(const uint2*)(ots[t] + base);
        const float4 bv = *(const float4*)(bias + t * W_OUT + lane * 4);
        float4 hv;
        hv.x = blo(u.x) + bv.x;
        hv.y = bhi(u.x) + bv.y;
        hv.z = blo(u.y) + bv.z;
        hv.w = bhi(u.y) + bv.w;
        v[t] = hv;
        p[t] = hv.x * aw.x + hv.y * aw.y + hv.z * aw.z + hv.w * aw.w;
    }
#pragma unroll
    for (int off = 1; off < 64; off <<= 1) {
        p[0] += __shfl_xor(p[0], off);
        p[1] += __shfl_xor(p[1], off);
        p[2] += __shfl_xor(p[2], off);
    }
    const float ab = att_b[0];
    const float a0 = p[0] + ab, a1 = p[1] + ab, a2 = p[2] + ab;
    float4 o;
    o.x = a0 * v[0].x + a1 * v[1].x + a2 * v[2].x;
    o.y = a0 * v[0].y + a1 * v[1].y + a2 * v[2].y;
    o.z = a0 * v[0].z + a1 * v[1].z + a2 * v[2].z;
    o.w = a0 * v[0].w + a1 * v[1].w + a2 * v[2].w;
    *(float4*)(out + base) = o;
}

// ---------------------------------------------------------------------------
extern "C" void kernel_launch(void* const* d_in, const int* in_sizes, int n_in,
                              void* d_out, int out_size, void* d_ws, size_t ws_size,
                              hipStream_t stream) {
    const float* x     = (const float*)d_in[0];
    const int*   adj   = (const int*)d_in[1];   // [3][2][N_EDGES]
    const float* Ws    = (const float*)d_in[2]; // [3][256][256]
    const float* a_l   = (const float*)d_in[3]; // [3][8][32]
    const float* a_r   = (const float*)d_in[4];
    const float* bias  = (const float*)d_in[5]; // [3][256]
    const float* att_w = (const float*)d_in[6]; // [256]
    const float* att_b = (const float*)d_in[7]; // [1]
    float* out = (float*)d_out;

    // Workspace (~145 MB).
    //   part (19.2 MB) aliases ot0: consumed by p2_csr before gather(0) writes ot0.
    //   H1 (25.6 MB) aliases ot2: H1 written by gemm(1) in F1, last read by
    //   gather(1) in F2; ot2 first written by gather(2) in G3. Serial stream.
    char* w = (char*)d_ws;
    unsigned short* xb = (unsigned short*)w; w += (size_t)N_NODES * W_IN * 2;   // 25.6 MB
    unsigned short* H0 = (unsigned short*)w; w += (size_t)N_NODES * W_OUT * 2;  // 25.6 MB
    unsigned short* Wt = (unsigned short*)w; w += (size_t)NUM_T * 65536 * 2;    // 0.39 MB
    unsigned short* ot0 = (unsigned short*)w; w += (size_t)N_NODES * W_OUT * 2; // 25.6 MB
    unsigned short* ot1 = (unsigned short*)w; w += (size_t)N_NODES * W_OUT * 2; // 25.6 MB
    unsigned short* ot2 = (unsigned short*)w; w += (size_t)N_NODES * W_OUT * 2; // 25.6 MB
    float* el0 = (float*)w; w += (size_t)N_NODES * HEADS * 4;   // 1.6 MB
    float* er0 = (float*)w; w += (size_t)N_NODES * HEADS * 4;   // 1.6 MB
    float* el1 = (float*)w; w += (size_t)N_NODES * HEADS * 4;   // 1.6 MB
    float* er1 = (float*)w; w += (size_t)N_NODES * HEADS * 4;   // 1.6 MB
    int* csr_src = (int*)w; w += (size_t)NUM_T * N_EDGES * 4;   // 9.6 MB
    int* row_ptr = (int*)w; w += (size_t)NUM_T * (N_NODES + 1) * 4;
    int* bucket_cnt = (int*)w; w += NUM_T * NB * 4;
    int* bucket_ptr = (int*)w; w += NUM_T * (NB + 1) * 4;
    int* bucket_cur = (int*)w; w += NUM_T * NB * 4;
    uint2* part = (uint2*)ot0;            // 19.2 MB alias
    unsigned short* H1 = ot2;             // 25.6 MB alias

    // --- setup: converts + two-level CSR build (all types at once) ---
    hipMemsetAsync(bucket_cnt, 0, NUM_T * NB * sizeof(int), stream);
    convert_x<<<12500, 256, 0, stream>>>(x, xb);
    convert_W<<<dim3(256, NUM_T), 256, 0, stream>>>(Ws, Wt);
    p1_hist<<<dim3(P1_BLOCKS, NUM_T), 256, 0, stream>>>(adj, bucket_cnt);
    p1_scan<<<1, 128, 0, stream>>>(bucket_cnt, bucket_ptr, bucket_cur);
    p1_scatter<<<dim3(P1_BLOCKS, NUM_T), 256, 0, stream>>>(adj, bucket_cur, part);
    p2_csr<<<dim3(NB_USED, NUM_T), 256, 0, stream>>>(part, bucket_ptr, row_ptr,
                                                     csr_src);

    // --- software pipeline over edge types: gemm(t+1) overlaps gather(t) ---
    // G0: gemm(0) -> H0/el0/er0
    gemm_fused<<<GEMM_BLOCKS, 256, 0, stream>>>(
        xb, Wt, a_l, a_r, H0, el0, er0);
    // F1: gemm(1) -> H1/el1/er1  ||  gather(0) from H0 -> ot0
    fused_gg<<<FUSED_BLOCKS, 256, 0, stream>>>(
        xb, Wt + 65536, a_l + 256, a_r + 256, H1, el1, er1,
        csr_src, row_ptr, el0, er0, H0, ot0);
    // F2: gemm(2) -> H0/el0/er0  ||  gather(1) from H1 -> ot1
    fused_gg<<<FUSED_BLOCKS, 256, 0, stream>>>(
        xb, Wt + 2 * 65536, a_l + 512, a_r + 512, H0, el0, er0,
        csr_src + N_EDGES, row_ptr + (N_NODES + 1), el1, er1, H1, ot1);
    // G3: gather(2) from H0 -> ot2 (overwrites H1 region after its last read)
    gat_gather<<<GATHER_BLOCKS, 256, 0, stream>>>(
        csr_src + 2 * (size_t)N_EDGES, row_ptr + 2 * (N_NODES + 1),
        el0, er0, H0, ot2);

    combine<<<GATHER_BLOCKS, 256, 0, stream>>>(ot0, ot1, ot2, bias, att_w,
                                               att_b, out);
}

// Round 3
// 464.465 us; speedup vs baseline: 1.3999x; 1.3999x over previous
//
#include <hip/hip_runtime.h>

#define N_NODES 50000
#define W_IN    256
#define W_OUT   256
#define HEADS   8
#define NUM_T   3
#define N_EDGES 800000
#define NEG_SLOPE 0.2f

#define NB      128           // coarse buckets (98 used)
#define BSH     9             // bucket = dst >> 9  (512 nodes/bucket)
#define BNODES  512
#define P1_EPT  16            // edges per thread in partition kernels
#define P1_CHUNK (256 * P1_EPT)   // 4096 edges per block
#define P1_BLOCKS ((N_EDGES + P1_CHUNK - 1) / P1_CHUNK)  // 196
#define NB_USED ((N_NODES + BNODES - 1) / BNODES)        // 98

#define GEMM_BLOCKS ((N_NODES + 63) / 64)       // 782
#define GATHER_BLOCKS ((N_NODES + 3) / 4)       // 12500
#define GEMM_SMEM 29696   // As 5120 + Bs 20480 + els 2048 + ers 2048

typedef __attribute__((ext_vector_type(8))) short bf16x8;
typedef __attribute__((ext_vector_type(4))) float f32x4;

__device__ __forceinline__ unsigned short f2b(float f) {
    unsigned u = __float_as_uint(f);
    u = (u + 0x7fffu + ((u >> 16) & 1u)) >> 16;
    return (unsigned short)u;
}
__device__ __forceinline__ float blo(unsigned u) { return __uint_as_float(u << 16); }
__device__ __forceinline__ float bhi(unsigned u) { return __uint_as_float(u & 0xffff0000u); }

// ---------------------------------------------------------------------------
// x fp32 -> bf16 (RNE). 12500 blocks * 256 threads * 4 elems = 12.8M exact.
// ---------------------------------------------------------------------------
__global__ __launch_bounds__(256) void convert_x(const float* __restrict__ x,
                                                 unsigned short* __restrict__ xb) {
    const size_t i = ((size_t)blockIdx.x * 256 + threadIdx.x) * 4;
    const float4 v = *(const float4*)(x + i);
    ushort4 o;
    o.x = f2b(v.x); o.y = f2b(v.y); o.z = f2b(v.z); o.w = f2b(v.w);
    *(ushort4*)(xb + i) = o;
}

// ---------------------------------------------------------------------------
// W fp32 [t][k][n] -> bf16 transposed [t][n][k].
// ---------------------------------------------------------------------------
__global__ __launch_bounds__(256) void convert_W(const float* __restrict__ Wsrc,
                                                 unsigned short* __restrict__ Wt) {
    const int t = blockIdx.y;
    const int gid = blockIdx.x * 256 + threadIdx.x;  // 0..65535
    const int k = gid >> 8, n = gid & 255;
    Wt[(size_t)t * 65536 + (size_t)n * 256 + k] = f2b(Wsrc[(size_t)t * 65536 + gid]);
}

// ---------------------------------------------------------------------------
// Partition level 1a: coarse histogram (LDS-aggregated).
// ---------------------------------------------------------------------------
__global__ __launch_bounds__(256) void p1_hist(const int* __restrict__ adj,
                                               int* __restrict__ bucket_cnt) {
    __shared__ int lh[NB];
    const int t = blockIdx.y;
    const int tid = threadIdx.x;
    if (tid < NB) lh[tid] = 0;
    __syncthreads();

    const int* dstp = adj + (size_t)t * 2 * N_EDGES + N_EDGES;
    const int e0 = blockIdx.x * P1_CHUNK + tid * P1_EPT;
#pragma unroll
    for (int i = 0; i < P1_EPT; ++i) {
        const int e = e0 + i;
        if (e < N_EDGES) atomicAdd(&lh[dstp[e] >> BSH], 1);
    }
    __syncthreads();
    if (tid < NB && lh[tid] > 0) atomicAdd(&bucket_cnt[t * NB + tid], lh[tid]);
}

// ---------------------------------------------------------------------------
// Partition level 1b: scan 128 bucket counts per type. One block, 128 thr.
// ---------------------------------------------------------------------------
__global__ __launch_bounds__(128) void p1_scan(const int* __restrict__ bucket_cnt,
                                               int* __restrict__ bucket_ptr,
                                               int* __restrict__ bucket_cur) {
    __shared__ int s[NB];
    const int tid = threadIdx.x;
    for (int t = 0; t < NUM_T; ++t) {
        const int v = bucket_cnt[t * NB + tid];
        s[tid] = v;
        __syncthreads();
        for (int off = 1; off < NB; off <<= 1) {
            int o = (tid >= off) ? s[tid - off] : 0;
            __syncthreads();
            s[tid] += o;
            __syncthreads();
        }
        const int incl = s[tid];
        const int excl = incl - v;
        bucket_ptr[t * (NB + 1) + tid] = excl;
        bucket_cur[t * NB + tid] = excl;
        if (tid == NB - 1) bucket_ptr[t * (NB + 1) + NB] = incl;
        __syncthreads();
    }
}

// ---------------------------------------------------------------------------
// Partition level 1c v2: LDS counting-sort, then contiguous flush.
// ---------------------------------------------------------------------------
__global__ __launch_bounds__(256) void p1_scatter(const int* __restrict__ adj,
                                                  int* __restrict__ bucket_cur,
                                                  uint2* __restrict__ part) {
    __shared__ int lh[NB];
    __shared__ int loff[NB];
    __shared__ int lbase[NB];
    __shared__ uint2 buf[P1_CHUNK];   // 32 KB
    const int t = blockIdx.y;
    const int tid = threadIdx.x;
    const int lane = tid & 63;
    const int wave = tid >> 6;
    if (tid < NB) lh[tid] = 0;
    __syncthreads();

    const int* srcp = adj + (size_t)t * 2 * N_EDGES;
    const int* dstp = srcp + N_EDGES;
    const int e0 = blockIdx.x * P1_CHUNK + tid * P1_EPT;

    int es[P1_EPT], ed[P1_EPT], rk[P1_EPT];
#pragma unroll
    for (int i = 0; i < P1_EPT; ++i) {
        const int e = e0 + i;
        if (e < N_EDGES) {
            es[i] = srcp[e];
            ed[i] = dstp[e];
            rk[i] = atomicAdd(&lh[ed[i] >> BSH], 1);
        } else {
            ed[i] = -1;
        }
    }
    __syncthreads();

    // global window reserve (one atomic per non-empty bucket)
    if (tid < NB && lh[tid] > 0)
        lbase[tid] = atomicAdd(&bucket_cur[t * NB + tid], lh[tid]);
    // local exclusive scan of lh -> loff (wave 0, 2 buckets/lane)
    if (wave == 0) {
        const int c0 = lh[lane * 2], c1 = lh[lane * 2 + 1];
        const int s = c0 + c1;
        int run = s;
        for (int off = 1; off < 64; off <<= 1) {
            const int o = __shfl_up(run, off);
            if (lane >= off) run += o;
        }
        const int base = run - s;
        loff[lane * 2] = base;
        loff[lane * 2 + 1] = base + c0;
    }
    __syncthreads();

#pragma unroll
    for (int i = 0; i < P1_EPT; ++i)
        if (ed[i] >= 0)
            buf[loff[ed[i] >> BSH] + rk[i]] =
                make_uint2((unsigned)es[i], (unsigned)ed[i]);
    __syncthreads();

    uint2* pt = part + (size_t)t * N_EDGES;
    int nvalid = N_EDGES - blockIdx.x * P1_CHUNK;
    if (nvalid > P1_CHUNK) nvalid = P1_CHUNK;
    for (int idx = tid; idx < nvalid; idx += 256) {
        const uint2 e = buf[idx];
        const int b = (int)(e.y >> BSH);
        pt[lbase[b] + (idx - loff[b])] = e;
    }
}

// ---------------------------------------------------------------------------
// Partition level 2: per-bucket local CSR. One block per (bucket, type).
// ---------------------------------------------------------------------------
__global__ __launch_bounds__(256) void p2_csr(const uint2* __restrict__ part,
                                              const int* __restrict__ bucket_ptr,
                                              int* __restrict__ row_ptr_all,
                                              int* __restrict__ csr_all) {
    __shared__ int sc[BNODES];
    const int b = blockIdx.x;
    const int t = blockIdx.y;
    const int tid = threadIdx.x;
    const int lane = tid & 63;
    const int wave = tid >> 6;

    const uint2* pt = part + (size_t)t * N_EDGES;
    int* row_ptr = row_ptr_all + (size_t)t * (N_NODES + 1);
    int* csr = csr_all + (size_t)t * N_EDGES;

    const int bp0 = bucket_ptr[t * (NB + 1) + b];
    const int bp1 = bucket_ptr[t * (NB + 1) + b + 1];
    const int node0 = b * BNODES;
    int nn = N_NODES - node0; if (nn > BNODES) nn = BNODES;

    sc[tid] = 0; sc[tid + 256] = 0;
    __syncthreads();

    for (int idx = bp0 + tid; idx < bp1; idx += 256)
        atomicAdd(&sc[pt[idx].y - node0], 1);
    __syncthreads();

    if (wave == 0) {
        int v[8], ex[8];
        int s = 0;
#pragma unroll
        for (int i = 0; i < 8; ++i) { v[i] = sc[lane * 8 + i]; ex[i] = s; s += v[i]; }
        int run = s;
        for (int off = 1; off < 64; off <<= 1) {
            int o = __shfl_up(run, off);
            if (lane >= off) run += o;
        }
        const int base = run - s;
#pragma unroll
        for (int i = 0; i < 8; ++i) sc[lane * 8 + i] = base + ex[i];
    }
    __syncthreads();

    for (int i = tid; i < nn; i += 256) row_ptr[node0 + i] = bp0 + sc[i];
    if (b == NB_USED - 1 && tid == 0) row_ptr[N_NODES] = N_EDGES;
    __syncthreads();

    for (int idx = bp0 + tid; idx < bp1; idx += 256) {
        const uint2 e = pt[idx];
        const int pos = bp0 + atomicAdd(&sc[e.y - node0], 1);
        csr[pos] = (int)e.x;
    }
}

// ---------------------------------------------------------------------------
// GEMM + fused attention-score body (proven round-0 inner code).
// smem carve: As[64*40] @0 (5120 B), Bs[256*40] @5120 (20480 B),
//             els[512] @25600 (2048 B), ers[512] @27648 (2048 B).
// ---------------------------------------------------------------------------
__device__ __forceinline__ void gemm_body(const int bm, const int tid,
                                          unsigned char* smem,
                                          const unsigned short* __restrict__ xb,
                                          const unsigned short* __restrict__ Wt,
                                          const float* __restrict__ al,
                                          const float* __restrict__ ar,
                                          unsigned short* __restrict__ H,
                                          float* __restrict__ el,
                                          float* __restrict__ er) {
    unsigned short* As = (unsigned short*)smem;
    unsigned short* Bs = (unsigned short*)(smem + 5120);
    float* els = (float*)(smem + 25600);
    float* ers = (float*)(smem + 27648);

    const int wave = tid >> 6;
    const int lane = tid & 63;
    const int quad = lane >> 4;
    const int l16 = lane & 15;
    const int m0 = bm * 64;

    f32x4 acc[4][4] = {};

    const int arow = tid >> 2;
    const int achunk = (tid & 3) * 8;
    int gm = m0 + arow;
    if (gm > N_NODES - 1) gm = N_NODES - 1;
    const unsigned short* aptr = xb + (size_t)gm * W_IN + achunk;

    for (int k0 = 0; k0 < W_IN; k0 += 32) {
        const uint4 av = *(const uint4*)(aptr + k0);
        *(uint4*)&As[arow * 40 + achunk] = av;
#pragma unroll
        for (int i = 0; i < 4; ++i) {
            const int idx = i * 256 + tid;
            const int brow = idx >> 2;
            const int bch = (idx & 3) * 8;
            const uint4 bv = *(const uint4*)(Wt + (size_t)brow * W_IN + k0 + bch);
            *(uint4*)&Bs[brow * 40 + bch] = bv;
        }
        __syncthreads();

        bf16x8 af[4], bfr[4];
#pragma unroll
        for (int mi = 0; mi < 4; ++mi)
            af[mi] = *(const bf16x8*)&As[(mi * 16 + l16) * 40 + quad * 8];
#pragma unroll
        for (int ni = 0; ni < 4; ++ni)
            bfr[ni] = *(const bf16x8*)&Bs[(wave * 64 + ni * 16 + l16) * 40 + quad * 8];
#pragma unroll
        for (int mi = 0; mi < 4; ++mi)
#pragma unroll
            for (int ni = 0; ni < 4; ++ni)
                acc[mi][ni] = __builtin_amdgcn_mfma_f32_16x16x32_bf16(
                    af[mi], bfr[ni], acc[mi][ni], 0, 0, 0);
        __syncthreads();
    }

#pragma unroll
    for (int mi = 0; mi < 4; ++mi)
#pragma unroll
        for (int reg = 0; reg < 4; ++reg) {
            const int gr = m0 + mi * 16 + quad * 4 + reg;
            if (gr < N_NODES)
#pragma unroll
                for (int ni = 0; ni < 4; ++ni)
                    H[(size_t)gr * W_OUT + wave * 64 + ni * 16 + l16] =
                        f2b(acc[mi][ni][reg]);
        }

    float al4[4], ar4[4];
#pragma unroll
    for (int ni = 0; ni < 4; ++ni) {
        const int c = wave * 64 + ni * 16 + l16;
        al4[ni] = al[c];
        ar4[ni] = ar[c];
    }
#pragma unroll
    for (int mi = 0; mi < 4; ++mi) {
        float pl[4][2] = {}, pr[4][2] = {};
#pragma unroll
        for (int ni = 0; ni < 4; ++ni) {
            const int hl = ni >> 1;
#pragma unroll
            for (int reg = 0; reg < 4; ++reg) {
                pl[reg][hl] += acc[mi][ni][reg] * al4[ni];
                pr[reg][hl] += acc[mi][ni][reg] * ar4[ni];
            }
        }
#pragma unroll
        for (int off = 1; off < 16; off <<= 1)
#pragma unroll
            for (int reg = 0; reg < 4; ++reg)
#pragma unroll
                for (int hl = 0; hl < 2; ++hl) {
                    pl[reg][hl] += __shfl_xor(pl[reg][hl], off);
                    pr[reg][hl] += __shfl_xor(pr[reg][hl], off);
                }
        if (l16 == 0)
#pragma unroll
            for (int reg = 0; reg < 4; ++reg)
#pragma unroll
                for (int hl = 0; hl < 2; ++hl) {
                    const int row = mi * 16 + quad * 4 + reg;
                    els[row * 8 + wave * 2 + hl] = pl[reg][hl];
                    ers[row * 8 + wave * 2 + hl] = pr[reg][hl];
                }
    }
    __syncthreads();

    int nn = N_NODES - m0; if (nn > 64) nn = 64;
    const int nn8 = nn * 8;
    const int i = tid * 4;
    if (i < nn8) {
        *(float4*)(el + (size_t)m0 * 8 + i) = *(float4*)&els[i];
        *(float4*)(er + (size_t)m0 * 8 + i) = *(float4*)&ers[i];
    }
}

// ---------------------------------------------------------------------------
// Gather v3 body (round-0 structure, 24 VGPR, proven 65.4 us/type):
// 2 edges per wave-instruction + 1-deep software pipeline.
// ---------------------------------------------------------------------------
__device__ __forceinline__ void gather_body(const int node, const int lane,
                                            const int* __restrict__ csr_src,
                                            const int* __restrict__ row_ptr,
                                            const float* __restrict__ el,
                                            const float* __restrict__ er,
                                            const unsigned short* __restrict__ H,
                                            unsigned short* __restrict__ ot) {
    const int half = lane >> 5;
    const int d8 = lane & 31;
    const int hh = d8 >> 2;

    const int beg = row_ptr[node];
    const int deg = row_ptr[node + 1] - beg;
    const float erv = er[(size_t)node * HEADS + hh];

    float2 acc[4] = {};
    float ssum = 0.f;

    if (deg > 0) {
        int mysrc = (lane < deg) ? csr_src[beg + lane] : 0;
        const int npairs = (deg + 1) >> 1;

        // prologue: load pair 0 (edge ei = half)
        int src0 = __shfl(mysrc, half);
        uint4 u0 = *(const uint4*)(H + (size_t)src0 * W_OUT + d8 * 8);
        float elv0 = el[(size_t)src0 * HEADS + hh];

        for (int q = 0; q < npairs; ++q) {
            int src1 = 0; uint4 u1 = u0; float elv1 = 0.f;
            const int q1 = q + 1;
            if (q1 < npairs) {
                if ((q1 & 31) == 0) {
                    const int cb = beg + (q1 >> 5) * 64;
                    mysrc = (cb + lane < beg + deg) ? csr_src[cb + lane] : 0;
                }
                src1 = __shfl(mysrc, (2 * q1 + half) & 63);
                u1 = *(const uint4*)(H + (size_t)src1 * W_OUT + d8 * 8);
                elv1 = el[(size_t)src1 * HEADS + hh];
            }
            float v = elv0 + erv;
            v = (v > 0.f) ? v : NEG_SLOPE * v;
            const float w = (2 * q + half < deg) ? __expf(v) : 0.f;
            acc[0].x += w * blo(u0.x); acc[0].y += w * bhi(u0.x);
            acc[1].x += w * blo(u0.y); acc[1].y += w * bhi(u0.y);
            acc[2].x += w * blo(u0.z); acc[2].y += w * bhi(u0.z);
            acc[3].x += w * blo(u0.w); acc[3].y += w * bhi(u0.w);
            ssum += w;
            src0 = src1; u0 = u1; elv0 = elv1;
        }
    }

#pragma unroll
    for (int i = 0; i < 4; ++i) {
        acc[i].x += __shfl_xor(acc[i].x, 32);
        acc[i].y += __shfl_xor(acc[i].y, 32);
    }
    ssum += __shfl_xor(ssum, 32);

    if (half == 0) {
        const float inv = 1.f / (ssum + 1e-9f);
        unsigned short o8[8];
#pragma unroll
        for (int i = 0; i < 4; ++i) {
            o8[2 * i]     = f2b(acc[i].x * inv);
            o8[2 * i + 1] = f2b(acc[i].y * inv);
        }
        *(uint4*)(ot + (size_t)node * W_OUT + d8 * 8) = *(const uint4*)o8;
    }
}

// ---------------------------------------------------------------------------
// Wrappers: t = blockIdx.y selects the edge type. Launched with grid.y=NUM_T
// (merged path) or grid.y=1 + pre-offset pointers (fallback path).
// ---------------------------------------------------------------------------
__global__ __launch_bounds__(256) void gemm_fused(const unsigned short* __restrict__ xb,
                                                  const unsigned short* __restrict__ Wt,
                                                  const float* __restrict__ al,
                                                  const float* __restrict__ ar,
                                                  unsigned short* __restrict__ H,
                                                  float* __restrict__ el,
                                                  float* __restrict__ er) {
    __shared__ __attribute__((aligned(16))) unsigned char smem[GEMM_SMEM];
    const size_t t = blockIdx.y;
    gemm_body(blockIdx.x, threadIdx.x, smem, xb,
              Wt + t * 65536, al + t * 256, ar + t * 256,
              H + t * (size_t)N_NODES * W_OUT,
              el + t * (size_t)N_NODES * HEADS,
              er + t * (size_t)N_NODES * HEADS);
}

__global__ __launch_bounds__(256) void gat_gather(const int* __restrict__ csr_src,
                                                  const int* __restrict__ row_ptr,
                                                  const float* __restrict__ el,
                                                  const float* __restrict__ er,
                                                  const unsigned short* __restrict__ H,
                                                  unsigned short* __restrict__ ot) {
    const int node = (blockIdx.x * blockDim.x + threadIdx.x) >> 6;
    if (node >= N_NODES) return;
    const size_t t = blockIdx.y;
    gather_body(node, threadIdx.x & 63,
                csr_src + t * N_EDGES, row_ptr + t * (N_NODES + 1),
                el + t * (size_t)N_NODES * HEADS,
                er + t * (size_t)N_NODES * HEADS,
                H + t * (size_t)N_NODES * W_OUT,
                ot + t * (size_t)N_NODES * W_OUT);
}

// ---------------------------------------------------------------------------
// Semantic attention combine: bf16 ot inputs (contiguous [3][N][256]), fp32 out.
// ---------------------------------------------------------------------------
__global__ __launch_bounds__(256) void combine(const unsigned short* __restrict__ ot,
                                               const float* __restrict__ bias,
                                               const float* __restrict__ att_w,
                                               const float* __restrict__ att_b,
                                               float* __restrict__ out) {
    const int gw = (blockIdx.x * blockDim.x + threadIdx.x) >> 6;
    const int lane = threadIdx.x & 63;
    if (gw >= N_NODES) return;

    const float4 aw = *(const float4*)(att_w + lane * 4);
    const size_t base = (size_t)gw * W_OUT + lane * 4;
    const size_t tstride = (size_t)N_NODES * W_OUT;

    float4 v[NUM_T];
    float p[NUM_T];
#pragma unroll
    for (int t = 0; t < NUM_T; ++t) {
        const uint2 u = *(const uint2*)(ot + t * tstride + base);
        const float4 bv = *(const float4*)(bias + t * W_OUT + lane * 4);
        float4 hv;
        hv.x = blo(u.x) + bv.x;
        hv.y = bhi(u.x) + bv.y;
        hv.z = blo(u.y) + bv.z;
        hv.w = bhi(u.y) + bv.w;
        v[t] = hv;
        p[t] = hv.x * aw.x + hv.y * aw.y + hv.z * aw.z + hv.w * aw.w;
    }
#pragma unroll
    for (int off = 1; off < 64; off <<= 1) {
        p[0] += __shfl_xor(p[0], off);
        p[1] += __shfl_xor(p[1], off);
        p[2] += __shfl_xor(p[2], off);
    }
    const float ab = att_b[0];
    const float a0 = p[0] + ab, a1 = p[1] + ab, a2 = p[2] + ab;
    float4 o;
    o.x = a0 * v[0].x + a1 * v[1].x + a2 * v[2].x;
    o.y = a0 * v[0].y + a1 * v[1].y + a2 * v[2].y;
    o.z = a0 * v[0].z + a1 * v[1].z + a2 * v[2].z;
    o.w = a0 * v[0].w + a1 * v[1].w + a2 * v[2].w;
    *(float4*)(out + base) = o;
}

// ---------------------------------------------------------------------------
extern "C" void kernel_launch(void* const* d_in, const int* in_sizes, int n_in,
                              void* d_out, int out_size, void* d_ws, size_t ws_size,
                              hipStream_t stream) {
    const float* x     = (const float*)d_in[0];
    const int*   adj   = (const int*)d_in[1];   // [3][2][N_EDGES]
    const float* Ws    = (const float*)d_in[2]; // [3][256][256]
    const float* a_l   = (const float*)d_in[3]; // [3][8][32]
    const float* a_r   = (const float*)d_in[4];
    const float* bias  = (const float*)d_in[5]; // [3][256]
    const float* att_w = (const float*)d_in[6]; // [256]
    const float* att_b = (const float*)d_in[7]; // [1]
    float* out = (float*)d_out;

    const size_t XB_B  = (size_t)N_NODES * W_IN * 2;          // 25.6 MB
    const size_t H_B   = (size_t)N_NODES * W_OUT * 2;         // 25.6 MB per type
    const size_t WT_B  = (size_t)NUM_T * 65536 * 2;           // 0.39 MB
    const size_t EL_B  = (size_t)N_NODES * HEADS * 4;         // 1.6 MB per type
    const size_t CSR_B = (size_t)NUM_T * N_EDGES * 4;         // 9.6 MB
    const size_t RP_B  = (size_t)NUM_T * (N_NODES + 1) * 4;   // 0.6 MB
    const size_t MISC_B = (size_t)NUM_T * (NB * 2 + NB + 1) * 4 + 4096;

    // merged path needs 3x H and 3x el/er: ~199.4 MB total
    const size_t need_merged = XB_B + NUM_T * H_B + WT_B + NUM_T * H_B /*ot*/
                             + 2 * NUM_T * EL_B + CSR_B + RP_B + MISC_B;
    const bool merged = (ws_size >= need_merged);

    char* w = (char*)d_ws;
    unsigned short* xb = (unsigned short*)w; w += XB_B;
    unsigned short* H  = (unsigned short*)w; w += merged ? NUM_T * H_B : H_B;
    unsigned short* Wt = (unsigned short*)w; w += WT_B;
    unsigned short* ot = (unsigned short*)w; w += NUM_T * H_B;  // [3][N][256] contiguous
    float* el = (float*)w; w += merged ? NUM_T * EL_B : EL_B;
    float* er = (float*)w; w += merged ? NUM_T * EL_B : EL_B;
    int* csr_src = (int*)w; w += CSR_B;
    int* row_ptr = (int*)w; w += RP_B;
    int* bucket_cnt = (int*)w; w += NUM_T * NB * 4;
    int* bucket_ptr = (int*)w; w += NUM_T * (NB + 1) * 4;
    int* bucket_cur = (int*)w; w += NUM_T * NB * 4;
    uint2* part = (uint2*)ot;   // 19.2 MB alias into ot[0]: consumed by p2_csr
                                // before any gather writes ot (serial stream)

    // --- setup: converts + two-level CSR build (all types at once) ---
    hipMemsetAsync(bucket_cnt, 0, NUM_T * NB * sizeof(int), stream);
    convert_x<<<12500, 256, 0, stream>>>(x, xb);
    convert_W<<<dim3(256, NUM_T), 256, 0, stream>>>(Ws, Wt);
    p1_hist<<<dim3(P1_BLOCKS, NUM_T), 256, 0, stream>>>(adj, bucket_cnt);
    p1_scan<<<1, 128, 0, stream>>>(bucket_cnt, bucket_ptr, bucket_cur);
    p1_scatter<<<dim3(P1_BLOCKS, NUM_T), 256, 0, stream>>>(adj, bucket_cur, part);
    p2_csr<<<dim3(NB_USED, NUM_T), 256, 0, stream>>>(part, bucket_ptr, row_ptr,
                                                     csr_src);

    if (merged) {
        // --- one dispatch per phase: 3 ramps/tails -> 1, fewer launch gaps ---
        gemm_fused<<<dim3(GEMM_BLOCKS, NUM_T), 256, 0, stream>>>(
            xb, Wt, a_l, a_r, H, el, er);
        gat_gather<<<dim3(GATHER_BLOCKS, NUM_T), 256, 0, stream>>>(
            csr_src, row_ptr, el, er, H, ot);
    } else {
        // --- fallback: proven round-0 per-type sequence (single H/el/er) ---
        for (int t = 0; t < NUM_T; ++t) {
            gemm_fused<<<dim3(GEMM_BLOCKS, 1), 256, 0, stream>>>(
                xb, Wt + (size_t)t * 65536, a_l + t * 256, a_r + t * 256,
                H, el, er);
            gat_gather<<<dim3(GATHER_BLOCKS, 1), 256, 0, stream>>>(
                csr_src + (size_t)t * N_EDGES,
                row_ptr + (size_t)t * (N_NODES + 1),
                el, er, H, ot + (size_t)t * N_NODES * W_OUT);
        }
    }

    combine<<<GATHER_BLOCKS, 256, 0, stream>>>(ot, bias, att_w, att_b, out);
}